// Round 6
// baseline (407.394 us; speedup 1.0000x reference)
//
#include <hip/hip_runtime.h>
#include <stdint.h>

#define NB 16
#define NC 512
#define NHW 4096

typedef unsigned short u16;
typedef __bf16 bf16x8 __attribute__((ext_vector_type(8)));
typedef float f32x4 __attribute__((ext_vector_type(4)));
typedef unsigned short u16x8 __attribute__((ext_vector_type(8)));
typedef unsigned short u16x4 __attribute__((ext_vector_type(4)));

#define AS1 __attribute__((address_space(1)))
#define AS3 __attribute__((address_space(3)))

__device__ __forceinline__ float bf2f(u16 h) {
    union { unsigned u; float f; } a; a.u = ((unsigned)h) << 16; return a.f;
}
__device__ __forceinline__ u16 f2bf(float f) {
    union { float f; unsigned u; } a; a.f = f;
    unsigned u = a.u;
    return (u16)((u + 0x7FFFu + ((u >> 16) & 1u)) >> 16);  // RNE
}

// ---------------- K0: fp32 -> bf16 copy of x ----------------
__global__ __launch_bounds__(256) void k_to_bf16(const float* __restrict__ x,
                                                 u16* __restrict__ xb) {
    int i = blockIdx.x * 256 + threadIdx.x;
    f32x4 v = ((const f32x4*)x)[i];
    u16x4 o;
    o[0] = f2bf(v[0]); o[1] = f2bf(v[1]); o[2] = f2bf(v[2]); o[3] = f2bf(v[3]);
    ((u16x4*)xb)[i] = o;
}

// Shared GEMM structure: 128x128 tile, BK=32, 256 threads (4 waves, 2x2 of
// 64x64), global_load_lds width-16 staging, ring-2 LDS (32 KB), raw s_barrier
// + counted vmcnt(4) (never 0 until epilogue), bank-conflict swizzle applied
// as pre-swizzled GLOBAL source + XOR'd ds_read (r4-verified: conflicts 0).
// Lessons: r3 tile-shrink = FETCH +85% net loss; r4 in-block pipelining at
// 1 block/CU = neutral (m131-m140 ceiling). Fix = split-K -> 4 blocks/CU
// with identical panel traffic; inter-block overlap (m114) hides latency.

#define STAGE_BODY(ASb, BSb, KO)                                               \
    {                                                                          \
        __builtin_amdgcn_global_load_lds((AS1 void*)(ag0 + (KO)),              \
            (AS3 void*)(&(ASb)[wave * 512]), 16, 0, 0);                        \
        __builtin_amdgcn_global_load_lds((AS1 void*)(ag1 + (KO)),              \
            (AS3 void*)(&(ASb)[2048 + wave * 512]), 16, 0, 0);                 \
        __builtin_amdgcn_global_load_lds((AS1 void*)(bg0 + (KO)),              \
            (AS3 void*)(&(BSb)[wave * 512]), 16, 0, 0);                        \
        __builtin_amdgcn_global_load_lds((AS1 void*)(bg1 + (KO)),              \
            (AS3 void*)(&(BSb)[2048 + wave * 512]), 16, 0, 0);                 \
    }

#define COMPUTE_BODY(ASb, BSb)                                                 \
    {                                                                          \
        bf16x8 af[4], bfr[4];                                                  \
        _Pragma("unroll")                                                      \
        for (int mi = 0; mi < 4; mi++)                                         \
            af[mi] = *(const bf16x8*)&(ASb)[(rm + mi * 16 + m16) * 32 + qsw8]; \
        _Pragma("unroll")                                                      \
        for (int ni = 0; ni < 4; ni++)                                         \
            bfr[ni] = *(const bf16x8*)&(BSb)[(rn + ni * 16 + m16) * 32 + qsw8];\
        _Pragma("unroll")                                                      \
        for (int mi = 0; mi < 4; mi++)                                         \
            _Pragma("unroll")                                                  \
            for (int ni = 0; ni < 4; ni++)                                     \
                acc[mi][ni] = __builtin_amdgcn_mfma_f32_16x16x32_bf16(         \
                    af[mi], bfr[ni], acc[mi][ni], 0, 0, 0);                    \
    }

#define WAIT4_BAR()                                                            \
    asm volatile("s_waitcnt vmcnt(4)" ::: "memory");                           \
    __builtin_amdgcn_s_barrier();                                              \
    __builtin_amdgcn_sched_barrier(0);

#define WAIT0_BAR()                                                            \
    asm volatile("s_waitcnt vmcnt(0)" ::: "memory");                           \
    __builtin_amdgcn_s_barrier();                                              \
    __builtin_amdgcn_sched_barrier(0);

#define END_BAR()                                                              \
    __builtin_amdgcn_sched_barrier(0);                                         \
    __builtin_amdgcn_s_barrier();

// ---------------- K1: P[s] = X[:,ks] X[:,ks]^T  (split-K=4, fp32 out) ------
// grid (4,4,64) = 1024 blocks = 4 blocks/CU. K=4096, Kc=1024.
__global__ __launch_bounds__(256, 4)
void k_gemm_xxt(const u16* __restrict__ Ab, float* __restrict__ P) {
    __shared__ u16 As[2][128 * 32];
    __shared__ u16 Bs[2][128 * 32];
    const int tid = threadIdx.x;
    const int wave = tid >> 6, lane = tid & 63;
    const int b = blockIdx.z >> 2;
    const int s = blockIdx.z & 3;
    const int kBeg = s << 10;                      // Kc = 1024
    const int kEnd = kBeg + 1024;

    const u16* A  = Ab + (size_t)b * NC * NHW + (size_t)blockIdx.x * 128 * NHW;
    const u16* Bm = Ab + (size_t)b * NC * NHW + (size_t)blockIdx.y * 128 * NHW;

    const int srow = tid >> 2;
    const int scol = ((tid & 3) ^ ((srow >> 1) & 3)) * 8;   // swizzled source
    const u16* ag0 = A  + (size_t)srow * NHW + scol;
    const u16* ag1 = ag0 + (size_t)64 * NHW;
    const u16* bg0 = Bm + (size_t)srow * NHW + scol;
    const u16* bg1 = bg0 + (size_t)64 * NHW;

    f32x4 acc[4][4];
#pragma unroll
    for (int i = 0; i < 4; i++)
#pragma unroll
        for (int j = 0; j < 4; j++) acc[i][j] = f32x4{0.f, 0.f, 0.f, 0.f};

    const int rm = (wave & 1) * 64;
    const int rn = (wave >> 1) * 64;
    const int m16 = lane & 15, quad = lane >> 4;
    const int qsw8 = (quad ^ ((m16 >> 1) & 3)) * 8;         // read-side XOR

    STAGE_BODY(As[0], Bs[0], kBeg);
    STAGE_BODY(As[1], Bs[1], kBeg + 32);

    for (int kg = kBeg; kg + 128 <= kEnd; kg += 64) {
        WAIT4_BAR();
        COMPUTE_BODY(As[0], Bs[0]);
        END_BAR();
        STAGE_BODY(As[0], Bs[0], kg + 64);
        WAIT4_BAR();
        COMPUTE_BODY(As[1], Bs[1]);
        END_BAR();
        STAGE_BODY(As[1], Bs[1], kg + 96);
    }
    WAIT4_BAR();
    COMPUTE_BODY(As[0], Bs[0]);
    WAIT0_BAR();
    COMPUTE_BODY(As[1], Bs[1]);

    // C/D layout: col = lane&15, row = (lane>>4)*4 + reg  (m89-verified)
    float* Po = P + ((size_t)s * NB + b) * NC * NC +
                ((size_t)blockIdx.x * 128) * NC + (size_t)blockIdx.y * 128;
    const int rq = quad * 4;
#pragma unroll
    for (int mi = 0; mi < 4; mi++)
#pragma unroll
        for (int ni = 0; ni < 4; ni++)
#pragma unroll
            for (int r = 0; r < 4; r++) {
                int row = rm + mi * 16 + rq + r;
                int col = rn + ni * 16 + m16;
                Po[(size_t)row * NC + col] = acc[mi][ni][r];
            }
}

// ---------------- K1c: S2 = S * S^T  (K=512, bf16 out, no split) -----------
__global__ __launch_bounds__(256, 4)
void k_gemm_ss(const u16* __restrict__ Sb, u16* __restrict__ S2) {
    __shared__ u16 As[2][128 * 32];
    __shared__ u16 Bs[2][128 * 32];
    const int tid = threadIdx.x;
    const int wave = tid >> 6, lane = tid & 63;
    const int b = blockIdx.z;

    const u16* A  = Sb + (size_t)b * NC * NC + (size_t)blockIdx.x * 128 * NC;
    const u16* Bm = Sb + (size_t)b * NC * NC + (size_t)blockIdx.y * 128 * NC;

    const int srow = tid >> 2;
    const int scol = ((tid & 3) ^ ((srow >> 1) & 3)) * 8;
    const u16* ag0 = A  + (size_t)srow * NC + scol;
    const u16* ag1 = ag0 + (size_t)64 * NC;
    const u16* bg0 = Bm + (size_t)srow * NC + scol;
    const u16* bg1 = bg0 + (size_t)64 * NC;

    f32x4 acc[4][4];
#pragma unroll
    for (int i = 0; i < 4; i++)
#pragma unroll
        for (int j = 0; j < 4; j++) acc[i][j] = f32x4{0.f, 0.f, 0.f, 0.f};

    const int rm = (wave & 1) * 64;
    const int rn = (wave >> 1) * 64;
    const int m16 = lane & 15, quad = lane >> 4;
    const int qsw8 = (quad ^ ((m16 >> 1) & 3)) * 8;

    STAGE_BODY(As[0], Bs[0], 0);
    STAGE_BODY(As[1], Bs[1], 32);

    for (int kg = 0; kg + 128 <= NC; kg += 64) {
        WAIT4_BAR();
        COMPUTE_BODY(As[0], Bs[0]);
        END_BAR();
        STAGE_BODY(As[0], Bs[0], kg + 64);
        WAIT4_BAR();
        COMPUTE_BODY(As[1], Bs[1]);
        END_BAR();
        STAGE_BODY(As[1], Bs[1], kg + 96);
    }
    WAIT4_BAR();
    COMPUTE_BODY(As[0], Bs[0]);
    WAIT0_BAR();
    COMPUTE_BODY(As[1], Bs[1]);

    u16* Co = S2 + (size_t)b * NC * NC + ((size_t)blockIdx.x * 128) * NC +
              (size_t)blockIdx.y * 128;
    const int rq = quad * 4;
#pragma unroll
    for (int mi = 0; mi < 4; mi++)
#pragma unroll
        for (int ni = 0; ni < 4; ni++)
#pragma unroll
            for (int r = 0; r < 4; r++) {
                int row = rm + mi * 16 + rq + r;
                int col = rn + ni * 16 + m16;
                Co[(size_t)row * NC + col] = f2bf(acc[mi][ni][r]);
            }
}

// ---------------- K1b: S = f2bf((P0+P1+P2+P3) * scale), bf16 ---------------
__global__ __launch_bounds__(256)
void k_reduce_S(const float* __restrict__ P, u16* __restrict__ S, float scale) {
    const size_t g = (size_t)blockIdx.x * 256 + threadIdx.x;  // f32x4 granule
    const size_t stride = (size_t)NB * NC * NC / 4;           // granules/partial
    f32x4 t = ((const f32x4*)P)[g];
    t += ((const f32x4*)P)[g + stride];
    t += ((const f32x4*)P)[g + 2 * stride];
    t += ((const f32x4*)P)[g + 3 * stride];
    u16x4 o;
    o[0] = f2bf(t[0] * scale); o[1] = f2bf(t[1] * scale);
    o[2] = f2bf(t[2] * scale); o[3] = f2bf(t[3] * scale);
    ((u16x4*)S)[g] = o;
}

// ---------------- K2: power iteration (one block per batch) ----------------
// vhat dir = (S2)^5 v0 = S^10 v0 (normalization is pure scaling; S=Ws/4096).
__global__ __launch_bounds__(1024, 1)
void k_power_iter(const u16* __restrict__ S2, const float* __restrict__ v0,
                  float* __restrict__ vhat) {
    const int b = blockIdx.x, tid = threadIdx.x;
    __shared__ float va[NC], vb[NC];
    __shared__ float part[NC][16];   // 32 KB
    __shared__ float red[16];
    const u16* Mb = S2 + (size_t)b * NC * NC;
    const int cg = tid & 15;   // col group: cols cg*8 + p*128 + j (p=0..3)
    const int r0 = tid >> 4;   // row-in-pass (0..63)
    if (tid < NC) va[tid] = v0[b * NC + tid];
    float* cur = va;
    float* nxt = vb;
    __syncthreads();

    for (int it = 0; it < 5; ++it) {
        float c[4][8];
#pragma unroll
        for (int p = 0; p < 4; p++) {
            f32x4 lo = *(const f32x4*)&cur[cg * 8 + p * 128];
            f32x4 hi = *(const f32x4*)&cur[cg * 8 + p * 128 + 4];
            c[p][0] = lo[0]; c[p][1] = lo[1]; c[p][2] = lo[2]; c[p][3] = lo[3];
            c[p][4] = hi[0]; c[p][5] = hi[1]; c[p][6] = hi[2]; c[p][7] = hi[3];
        }
#pragma unroll 2
        for (int pass = 0; pass < 8; ++pass) {
            const int r = pass * 64 + r0;
            const u16* row = Mb + (size_t)r * NC + cg * 8;
            u16x8 m[4];
#pragma unroll
            for (int p = 0; p < 4; p++) m[p] = *(const u16x8*)(row + p * 128);
            float a0 = 0.f, a1 = 0.f, a2 = 0.f, a3 = 0.f;
#pragma unroll
            for (int j = 0; j < 8; j++) {
                a0 += bf2f(m[0][j]) * c[0][j];
                a1 += bf2f(m[1][j]) * c[1][j];
                a2 += bf2f(m[2][j]) * c[2][j];
                a3 += bf2f(m[3][j]) * c[3][j];
            }
            part[r][cg] = (a0 + a1) + (a2 + a3);
        }
        __syncthreads();
        if (tid < NC) {
            f32x4 s0 = *(const f32x4*)&part[tid][0];
            f32x4 s1 = *(const f32x4*)&part[tid][4];
            f32x4 s2 = *(const f32x4*)&part[tid][8];
            f32x4 s3 = *(const f32x4*)&part[tid][12];
            f32x4 s = (s0 + s1) + (s2 + s3);
            nxt[tid] = (s[0] + s[1]) + (s[2] + s[3]);
        }
        __syncthreads();
        float* t = cur; cur = nxt; nxt = t;
    }

    // normalize v10 -> vhat
    float mv = (tid < NC) ? cur[tid] : 0.f;
    float x = mv * mv;
#pragma unroll
    for (int o = 32; o > 0; o >>= 1) x += __shfl_down(x, o, 64);
    if ((tid & 63) == 0) red[tid >> 6] = x;
    __syncthreads();
    float n = red[0];
#pragma unroll
    for (int w = 1; w < 16; w++) n += red[w];
    if (tid < NC) vhat[b * NC + tid] = mv * rsqrtf(n);
}

// ---------------- K3: t[n] = sum_c xb[b][c][n] * vhat[b][c]  (c-split x4) ---
__global__ __launch_bounds__(256)
void k_compute_t(const u16* __restrict__ xb, const float* __restrict__ vhat,
                 float* __restrict__ tp) {
    const int b = blockIdx.z, cc = blockIdx.y, nc = blockIdx.x, tid = threadIdx.x;
    __shared__ float vsh[128];
    if (tid < 128) vsh[tid] = vhat[b * NC + cc * 128 + tid];
    __syncthreads();
    const int n0 = nc * 2048 + tid * 8;
    const u16* xp = xb + (size_t)b * NC * NHW + (size_t)cc * 128 * NHW + n0;
    float acc[8] = {0.f, 0.f, 0.f, 0.f, 0.f, 0.f, 0.f, 0.f};
    for (int c = 0; c < 128; c++) {
        u16x8 w = *(const u16x8*)xp;
        xp += NHW;
        float vc = vsh[c];
#pragma unroll
        for (int j = 0; j < 8; j++) acc[j] += bf2f(w[j]) * vc;
    }
    float* dst = tp + (size_t)(b * 4 + cc) * NHW + n0;
    *(f32x4*)dst       = f32x4{acc[0], acc[1], acc[2], acc[3]};
    *(f32x4*)(dst + 4) = f32x4{acc[4], acc[5], acc[6], acc[7]};
}

// ---------------- K3b: tsum = sum_p tp; sinv = 1/||tsum|| (u-norm) ---------
__global__ __launch_bounds__(1024, 1)
void k_tnorm(const float* __restrict__ tp, float* __restrict__ tsum,
             float* __restrict__ sinv) {
    const int b = blockIdx.x, tid = threadIdx.x;
    __shared__ float red[16];
    const int n0 = tid * 4;  // 1024 threads x 4 = 4096
    f32x4 s = f32x4{0.f, 0.f, 0.f, 0.f};
#pragma unroll
    for (int p = 0; p < 4; p++)
        s += *(const f32x4*)(tp + (size_t)(b * 4 + p) * NHW + n0);
    *(f32x4*)(tsum + (size_t)b * NHW + n0) = s;
    float ss = s[0] * s[0] + s[1] * s[1] + s[2] * s[2] + s[3] * s[3];
#pragma unroll
    for (int o = 32; o > 0; o >>= 1) ss += __shfl_down(ss, o, 64);
    if ((tid & 63) == 0) red[tid >> 6] = ss;
    __syncthreads();
    if (tid == 0) {
        float n = red[0];
#pragma unroll
        for (int w = 1; w < 16; w++) n += red[w];
        sinv[b] = rsqrtf(n);
    }
}

// ---------------- K4: out = x + tsum[n] * (vhat[c] * sinv[b]) ----------------
__global__ __launch_bounds__(256)
void k_epilogue(const float* __restrict__ x, const float* __restrict__ tsum,
                const float* __restrict__ vhat, const float* __restrict__ sinv,
                float* __restrict__ out) {
    const int b = blockIdx.z, cc = blockIdx.y, nc = blockIdx.x, tid = threadIdx.x;
    __shared__ float tl[1024];
    __shared__ float cf[64];
    const int nbase = nc * 1024, cbase = cc * 64;
    const float si = sinv[b];
    for (int i = tid; i < 1024; i += 256)
        tl[i] = tsum[(size_t)b * NHW + nbase + i];
    if (tid < 64) cf[tid] = vhat[b * NC + cbase + tid] * si;
    __syncthreads();
    f32x4 tv = ((const f32x4*)tl)[tid];
    for (int rr = 0; rr < 64; rr++) {
        size_t off = ((size_t)(b * NC + cbase + rr)) * NHW + nbase + tid * 4;
        f32x4 xv = *(const f32x4*)(x + off);
        float c = cf[rr];
        f32x4 o = xv + tv * c;
        *(f32x4*)(out + off) = o;
    }
}

extern "C" void kernel_launch(void* const* d_in, const int* in_sizes, int n_in,
                              void* d_out, int out_size, void* d_ws, size_t ws_size,
                              hipStream_t stream) {
    const float* x  = (const float*)d_in[0];   // (16,512,64,64) fp32
    const float* v0 = (const float*)d_in[1];   // (16,512,1) fp32
    float* out = (float*)d_out;

    char* ws = (char*)d_ws;
    u16* xb     = (u16*)ws;                                   // 64 MiB bf16 x
    u16* S      = (u16*)(ws + 67108864);                      // 8 MiB  Ws/4096
    u16* S2     = (u16*)(ws + 67108864 + 8388608);            // 8 MiB  S^2
    float* vhat = (float*)(ws + 83886080);                    // 32 KiB
    float* tp   = (float*)(ws + 83886080 + 65536);            // 1 MiB (4 c-partials)
    float* tsum = (float*)(ws + 83886080 + 65536 + 1048576);  // 256 KiB
    float* sinv = (float*)(ws + 83886080 + 65536 + 1048576 + 262144);  // 64 B

    // d_out (128 MiB) doubles as split-K fp32 partial scratch (4 x 16.8 MiB);
    // k_epilogue fully overwrites it afterwards.
    float* Pp = (float*)d_out;

    k_to_bf16<<<dim3(32768), dim3(256), 0, stream>>>(x, xb);
    // P[s] = X[:, ks] X[:, ks]^T  (split-K=4: 1024 blocks = 4 blocks/CU)
    k_gemm_xxt<<<dim3(4, 4, NB * 4), dim3(256), 0, stream>>>(xb, Pp);
    // S = (P0+P1+P2+P3) / 4096, bf16
    k_reduce_S<<<dim3(4096), dim3(256), 0, stream>>>(Pp, S, 1.f / 4096.f);
    // S2 = S * S^T = S * S   (M=N=K=512, S symmetric)
    k_gemm_ss<<<dim3(4, 4, NB), dim3(256), 0, stream>>>(S, S2);
    k_power_iter<<<dim3(NB), dim3(1024), 0, stream>>>(S2, v0, vhat);
    k_compute_t<<<dim3(2, 4, NB), dim3(256), 0, stream>>>(xb, vhat, tp);
    k_tnorm<<<dim3(NB), dim3(1024), 0, stream>>>(tp, tsum, sinv);
    k_epilogue<<<dim3(4, 8, NB), dim3(256), 0, stream>>>(x, tsum, vhat, sinv, out);
}